// Round 8
// baseline (286.007 us; speedup 1.0000x reference)
//
#include <hip/hip_runtime.h>
#include <hip/hip_bf16.h>

typedef _Float16 h8 __attribute__((ext_vector_type(8)));
typedef float f4 __attribute__((ext_vector_type(4)));

#define N_TOK 65536
#define DIM 256
#define KCODES 1024
#define HWSZ 4096

// async global->LDS, 16B per lane. LDS dest = wave-uniform base + lane*16.
__device__ __forceinline__ void gll16(const void* g, void* l) {
    __builtin_amdgcn_global_load_lds((const __attribute__((address_space(1))) void*)g,
                                     (__attribute__((address_space(3))) void*)l, 16, 0, 0);
}

// Fragment layout (A and B operands, 16x16x32 f16 MFMA):
//   element (n, d) -> granule G = ((n>>4)*8 + (d>>5))*64 + ((d>>3)&3)*16 + (n&15),
//   half j = d&7 inside the 16B granule. Conflict-free ds_read_b128, linear gll16.

// ---------------- K0a: embedding -> fragment-layout fp16 hi/lo ---------------
__global__ void k_prep_frag(const float* __restrict__ emb, _Float16* __restrict__ BhF,
                            _Float16* __restrict__ BlF) {
    int gi = blockIdx.x * 256 + threadIdx.x;      // granule index, 0..32767
    int kb = gi >> 9;
    int s = (gi >> 6) & 7;
    int dq = (gi >> 4) & 3;
    int r = gi & 15;
    int code = kb * 16 + r;
    int d0 = s * 32 + dq * 8;
    const float* src = emb + (size_t)code * DIM + d0;
    float4 x0 = *(const float4*)(src);
    float4 x1 = *(const float4*)(src + 4);
    float xs[8] = {x0.x, x0.y, x0.z, x0.w, x1.x, x1.y, x1.z, x1.w};
    h8 hi, lo;
#pragma unroll
    for (int j = 0; j < 8; ++j) {
        _Float16 h = (_Float16)xs[j];
        hi[j] = h;
        lo[j] = (_Float16)(xs[j] - (float)h);
    }
    *(h8*)(BhF + (size_t)gi * 8) = hi;
    *(h8*)(BlF + (size_t)gi * 8) = lo;
}

// ---------------- K0b: e_sq ---------------------------------------------------
__global__ void k_esq(const float* __restrict__ emb, float* __restrict__ e_sq) {
    int t = threadIdx.x;
    int code = blockIdx.x * 4 + (t >> 6);
    int l = t & 63;
    float4 v = *(const float4*)(emb + (size_t)code * DIM + l * 4);
    float s = v.x * v.x + v.y * v.y + v.z * v.z + v.w * v.w;
#pragma unroll
    for (int off = 32; off >= 1; off >>= 1) s += __shfl_xor(s, off);
    if (l == 0) e_sq[code] = s;
}

// ------- K1: transpose z[B,C,H,W] -> enc[N,C] + fragment fp16 hi/lo ----------
__global__ void k_transpose(const float* __restrict__ z, float* __restrict__ enc,
                            _Float16* __restrict__ AhF, _Float16* __restrict__ AlF) {
    __shared__ float T[64][65];
    int blk = blockIdx.x;
    int b = blk >> 8;
    int rem = blk & 255;
    int c0 = (rem >> 6) * 64;
    int hw0 = (rem & 63) * 64;
    int t = threadIdx.x;
    const float* zp = z + (size_t)b * DIM * HWSZ;
    {
        int hw4 = (t & 15) * 4, cl = t >> 4;
#pragma unroll
        for (int i = 0; i < 4; ++i) {
            int c = cl + i * 16;
            float4 v = *(const float4*)(zp + (size_t)(c0 + c) * HWSZ + hw0 + hw4);
            T[c][hw4 + 0] = v.x; T[c][hw4 + 1] = v.y;
            T[c][hw4 + 2] = v.z; T[c][hw4 + 3] = v.w;
        }
    }
    __syncthreads();
    // enc fp32 (output 0)
    {
        int c4 = (t & 15) * 4, hwl = t >> 4;
#pragma unroll
        for (int i = 0; i < 4; ++i) {
            int hw = hwl + i * 16;
            float4 v;
            v.x = T[c4 + 0][hw]; v.y = T[c4 + 1][hw];
            v.z = T[c4 + 2][hw]; v.w = T[c4 + 3][hw];
            *(float4*)(enc + (size_t)(b * HWSZ + hw0 + hw) * DIM + c0 + c4) = v;
        }
    }
    // fragment-layout fp16 hi/lo
    {
        int base_nb = b * 256 + (hw0 >> 4);
#pragma unroll
        for (int i = 0; i < 2; ++i) {
            int gidx = i * 256 + t;
            int nbi = gidx >> 7;
            int si = (gidx >> 6) & 1;
            int dq = (gidx >> 4) & 3;
            int r = gidx & 15;
            int hwl = nbi * 16 + r;
            int cl = si * 32 + dq * 8;
            h8 hi, lo;
#pragma unroll
            for (int j = 0; j < 8; ++j) {
                float x = T[cl + j][hwl];
                _Float16 h = (_Float16)x;
                hi[j] = h;
                lo[j] = (_Float16)(x - (float)h);
            }
            size_t G = (((size_t)(base_nb + nbi) * 8) + (c0 >> 5) + si) * 64 + dq * 16 + r;
            *(h8*)(AhF + G * 8) = hi;
            *(h8*)(AlF + G * 8) = lo;
        }
    }
}

// ---- K2: full GEMM+argmin: 256 rows/block x ALL 1024 codes, 64 phases -------
#define WAITV(n) asm volatile("s_waitcnt vmcnt(" #n ")" ::: "memory")
#define BARRIER __builtin_amdgcn_s_barrier()
#define PRIO1 __builtin_amdgcn_s_setprio(1)
#define PRIO0 __builtin_amdgcn_s_setprio(0)

extern __shared__ char SB[];   // [0,128K): 4 bufs x 32 KB; [128K..137K): reduce scratch

__global__ __launch_bounds__(1024)
void k_gemm_argmin(const _Float16* __restrict__ AhF, const _Float16* __restrict__ AlF,
                   const _Float16* __restrict__ BhF, const _Float16* __restrict__ BlF,
                   const float* __restrict__ e_sq, const float* __restrict__ emb,
                   float* __restrict__ out1, float* __restrict__ out2,
                   int* __restrict__ idxI) {
    int rowTile = blockIdx.x;
    int r0 = rowTile * 256;
    int t = threadIdx.x;
    int w = t >> 6, l = t & 63;           // 16 waves
    int wm = w >> 2, wn = w & 3;          // wave tile 64x64
    int l16 = l & 15, lhi = l >> 4;

    const char* gAh = (const char*)AhF + (((size_t)(rowTile * 16 + w)) << 13) + (l << 4);
    const char* gAl = (const char*)AlF + (((size_t)(rowTile * 16 + w)) << 13) + (l << 4);
    const char* gBh = (const char*)BhF + (((size_t)w) << 13) + (l << 4);
    const char* gBl = (const char*)BlF + (((size_t)w) << 13) + (l << 4);

    float* smV = (float*)(SB + 131072);   // [4][256]
    int*   smI = (int*)(SB + 135168);     // [4][256]
    int*  sidx = (int*)(SB + 139264);     // [256]

// issue stage for within-ct phase q2 (0..15) with B colTile byte offset ctoff
#define ISSUE_Q(ctoff, q2) do { \
    const int s_ = (q2) >> 1; \
    char* bp_ = SB + ((q2) & 3) * 32768; \
    const char* a_ = ((q2) & 1) ? gAl : gAh; \
    const char* b_ = ((q2) & 1) ? gBl : gBh; \
    gll16(a_ + (s_ << 10), bp_ + (w << 10)); \
    gll16(b_ + (ctoff) + (s_ << 10), bp_ + 16384 + (w << 10)); \
} while (0)

#define MFMA16(A_, B_) { _Pragma("unroll") for (int mf = 0; mf < 4; ++mf) \
    _Pragma("unroll") for (int nf = 0; nf < 4; ++nf) \
        acc[mf][nf] = __builtin_amdgcn_mfma_f32_16x16x32_f16(A_[mf], B_[nf], acc[mf][nf], 0, 0, 0); }

// phase q (0..15 compile-time); ct runtime. even: hh; odd: hl then lh.
#define PHASE(q) { \
    if ((q) == 14) { if (lastct) { WAITV(2); } else { WAITV(4); } } \
    else if ((q) == 15) { if (lastct) { WAITV(0); } else { WAITV(4); } } \
    else { WAITV(4); } \
    BARRIER; \
    if ((q) <= 12) { ISSUE_Q(ctoff, (q) + 3); } \
    else if (!lastct) { ISSUE_Q(ctoffN, (q) - 13); } \
    const char* bp_ = SB + ((q) & 3) * 32768; \
    if (((q) & 1) == 0) { \
        _Pragma("unroll") for (int mf = 0; mf < 4; ++mf) \
            ah[mf] = *(const h8*)(bp_ + ((wm * 4 + mf) << 10) + (l << 4)); \
        _Pragma("unroll") for (int nf = 0; nf < 4; ++nf) \
            bh[nf] = *(const h8*)(bp_ + 16384 + ((wn * 4 + nf) << 10) + (l << 4)); \
        PRIO1; MFMA16(ah, bh); PRIO0; \
    } else { \
        h8 xl[4]; \
        _Pragma("unroll") for (int nf = 0; nf < 4; ++nf) \
            xl[nf] = *(const h8*)(bp_ + 16384 + ((wn * 4 + nf) << 10) + (l << 4)); \
        PRIO1; MFMA16(ah, xl); PRIO0; \
        _Pragma("unroll") for (int mf = 0; mf < 4; ++mf) \
            xl[mf] = *(const h8*)(bp_ + ((wm * 4 + mf) << 10) + (l << 4)); \
        PRIO1; MFMA16(xl, bh); PRIO0; \
    } }

    f4 acc[4][4];
#pragma unroll
    for (int i = 0; i < 4; ++i)
#pragma unroll
        for (int j = 0; j < 4; ++j) acc[i][j] = (f4)0.0f;

    h8 ah[4], bh[4];
    float rV = 3.4e38f;
    int rI = 0;

    // prologue: 3 phases in flight
    ISSUE_Q(0, 0); ISSUE_Q(0, 1); ISSUE_Q(0, 2);

    for (int ct = 0; ct < 4; ++ct) {
        const bool lastct = (ct == 3);
        const int ctoff = ct << 17, ctoffN = (ct + 1) << 17;

        PHASE(0)  PHASE(1)  PHASE(2)  PHASE(3)
        PHASE(4)  PHASE(5)  PHASE(6)  PHASE(7)
        PHASE(8)  PHASE(9)  PHASE(10) PHASE(11)
        PHASE(12) PHASE(13) PHASE(14) PHASE(15)

        // ---- fold argmin for this colTile's 256 codes ----
        float esqv[4];
#pragma unroll
        for (int nf = 0; nf < 4; ++nf)
            esqv[nf] = e_sq[ct * 256 + wn * 64 + nf * 16 + l16];
#pragma unroll
        for (int mf = 0; mf < 4; ++mf) {
#pragma unroll
            for (int rg = 0; rg < 4; ++rg) {
                float bv = 3.4e38f;
                int bi = 0;
#pragma unroll
                for (int nf = 0; nf < 4; ++nf) {
                    float v = fmaf(-2.0f, acc[mf][nf][rg], esqv[nf]);
                    int ci = ct * 256 + wn * 64 + nf * 16 + l16;
                    if (v < bv) { bv = v; bi = ci; }   // ascending ci + strict < => lowest idx
                }
#pragma unroll
                for (int off = 1; off < 16; off <<= 1) {
                    float vv = __shfl_xor(bv, off);
                    int ii = __shfl_xor(bi, off);
                    if (vv < bv || (vv == bv && ii < bi)) { bv = vv; bi = ii; }
                }
                if (l16 == 0) {
                    int rloc = wm * 64 + mf * 16 + lhi * 4 + rg;
                    smV[wn * 256 + rloc] = bv;
                    smI[wn * 256 + rloc] = bi;
                }
            }
        }
#pragma unroll
        for (int mf = 0; mf < 4; ++mf)
#pragma unroll
            for (int nf = 0; nf < 4; ++nf) acc[mf][nf] = (f4)0.0f;
        __syncthreads();
        if (t < 256) {
#pragma unroll
            for (int wn2 = 0; wn2 < 4; ++wn2) {
                float vv = smV[wn2 * 256 + t];
                int ii = smI[wn2 * 256 + t];
                if (vv < rV || (vv == rV && ii < rI)) { rV = vv; rI = ii; }
            }
        }
        __syncthreads();
    }

    // ---- epilogue: write index outputs + gather quantized_flat rows ----
    if (t < 256) {
        int n = r0 + t;
        out2[n] = (float)rI;
        idxI[n] = rI;
        sidx[t] = rI;
    }
    __syncthreads();
    {
        int row = t >> 2, q = t & 3;
        int idx = sidx[row];
        const float* src = emb + (size_t)idx * DIM + q * 64;
        float* dst = out1 + (size_t)(r0 + row) * DIM + q * 64;
#pragma unroll
        for (int j = 0; j < 16; ++j)
            *(float4*)(dst + j * 4) = *(const float4*)(src + j * 4);
    }
}

// ---------------- K3: quantized[B,C,H,W] via LDS transpose -------------------
__global__ void k_out3(const float* __restrict__ emb, const int* __restrict__ idxI,
                       float* __restrict__ out3) {
    __shared__ float E[32][257];
    int blk = blockIdx.x;
    int b = blk >> 7, hwt = blk & 127;
    int hw0 = hwt * 32;
    int n0 = b * HWSZ + hw0;
    int t = threadIdx.x;
    {
        int r = t >> 3, oct = t & 7;
        int idx = idxI[n0 + r];
        const float* src = emb + (size_t)idx * DIM + oct * 32;
#pragma unroll
        for (int i = 0; i < 8; ++i) {
            float4 v = *(const float4*)(src + i * 4);
            E[r][oct * 32 + i * 4 + 0] = v.x;
            E[r][oct * 32 + i * 4 + 1] = v.y;
            E[r][oct * 32 + i * 4 + 2] = v.z;
            E[r][oct * 32 + i * 4 + 3] = v.w;
        }
    }
    __syncthreads();
    {
        int w = t >> 6, l = t & 63;
        int ch = l >> 5, hw = l & 31;
        float* dst = out3 + (size_t)b * DIM * HWSZ + hw0 + hw;
#pragma unroll
        for (int it = 0; it < 32; ++it) {
            int c = w * 64 + it * 2 + ch;
            dst[(size_t)c * HWSZ] = E[hw][c];
        }
    }
}

extern "C" void kernel_launch(void* const* d_in, const int* in_sizes, int n_in,
                              void* d_out, int out_size, void* d_ws, size_t ws_size,
                              hipStream_t stream) {
    const float* z = (const float*)d_in[0];
    const float* emb = (const float*)d_in[1];
    float* out = (float*)d_out;
    float* out0 = out;                    // encoded_flat  [65536,256]
    float* out1 = out + 16777216;         // quantized_flat[65536,256]
    float* out2 = out + 33554432;         // indices       [65536] (as float)
    float* out3 = out + 33619968;         // quantized     [16,256,64,64]

    // A-operand fp16 hi/lo scratch lives in the out3 region (64 MB); out3 is
    // written last by k_out3 (after gemm has consumed A). out1 region stays
    // free for the gemm epilogue's gather writes.
    _Float16* AhF = (_Float16*)out3;
    _Float16* AlF = (_Float16*)(out3 + 8388608);

    char* ws = (char*)d_ws;
    _Float16* BhF = (_Float16*)(ws);                 // 512 KB
    _Float16* BlF = (_Float16*)(ws + 524288);        // 512 KB
    float* e_sq = (float*)(ws + 1048576);            // 4 KB
    int* idxI = (int*)(ws + 1052672);                // 256 KB

    hipFuncSetAttribute((const void*)k_gemm_argmin,
                        hipFuncAttributeMaxDynamicSharedMemorySize, 140288);

    k_prep_frag<<<128, 256, 0, stream>>>(emb, BhF, BlF);
    k_esq<<<256, 256, 0, stream>>>(emb, e_sq);
    k_transpose<<<4096, 256, 0, stream>>>(z, out0, AhF, AlF);
    k_gemm_argmin<<<256, 1024, 140288, stream>>>(AhF, AlF, BhF, BlF, e_sq, emb,
                                                 out1, out2, idxI);
    k_out3<<<2048, 256, 0, stream>>>(emb, idxI, out3);
}

// Round 9
// 205.558 us; speedup vs baseline: 1.3914x; 1.3914x over previous
//
#include <hip/hip_runtime.h>
#include <hip/hip_bf16.h>

typedef _Float16 h8 __attribute__((ext_vector_type(8)));
typedef float f4 __attribute__((ext_vector_type(4)));

#define N_TOK 65536
#define DIM 256
#define KCODES 1024
#define HWSZ 4096

// async global->LDS, 16B per lane. LDS dest = wave-uniform base + lane*16.
__device__ __forceinline__ void gll16(const void* g, void* l) {
    __builtin_amdgcn_global_load_lds((const __attribute__((address_space(1))) void*)g,
                                     (__attribute__((address_space(3))) void*)l, 16, 0, 0);
}

// Fragment layout (A and B operands, 16x16x32 f16 MFMA):
//   element (n, d) -> granule G = ((n>>4)*8 + (d>>5))*64 + ((d>>3)&3)*16 + (n&15),
//   half j = d&7 inside the 16B granule. Conflict-free ds_read_b128, linear gll16.

// ---------------- K0a: embedding -> fragment-layout fp16 hi/lo ---------------
__global__ void k_prep_frag(const float* __restrict__ emb, _Float16* __restrict__ BhF,
                            _Float16* __restrict__ BlF) {
    int gi = blockIdx.x * 256 + threadIdx.x;      // granule index, 0..32767
    int kb = gi >> 9;
    int s = (gi >> 6) & 7;
    int dq = (gi >> 4) & 3;
    int r = gi & 15;
    int code = kb * 16 + r;
    int d0 = s * 32 + dq * 8;
    const float* src = emb + (size_t)code * DIM + d0;
    float4 x0 = *(const float4*)(src);
    float4 x1 = *(const float4*)(src + 4);
    float xs[8] = {x0.x, x0.y, x0.z, x0.w, x1.x, x1.y, x1.z, x1.w};
    h8 hi, lo;
#pragma unroll
    for (int j = 0; j < 8; ++j) {
        _Float16 h = (_Float16)xs[j];
        hi[j] = h;
        lo[j] = (_Float16)(xs[j] - (float)h);
    }
    *(h8*)(BhF + (size_t)gi * 8) = hi;
    *(h8*)(BlF + (size_t)gi * 8) = lo;
}

// ---------------- K0b: e_sq ---------------------------------------------------
__global__ void k_esq(const float* __restrict__ emb, float* __restrict__ e_sq) {
    int t = threadIdx.x;
    int code = blockIdx.x * 4 + (t >> 6);
    int l = t & 63;
    float4 v = *(const float4*)(emb + (size_t)code * DIM + l * 4);
    float s = v.x * v.x + v.y * v.y + v.z * v.z + v.w * v.w;
#pragma unroll
    for (int off = 32; off >= 1; off >>= 1) s += __shfl_xor(s, off);
    if (l == 0) e_sq[code] = s;
}

// ------- K1: transpose z[B,C,H,W] -> enc[N,C] + fragment fp16 hi/lo ----------
__global__ void k_transpose(const float* __restrict__ z, float* __restrict__ enc,
                            _Float16* __restrict__ AhF, _Float16* __restrict__ AlF) {
    __shared__ float T[64][65];
    int blk = blockIdx.x;
    int b = blk >> 8;
    int rem = blk & 255;
    int c0 = (rem >> 6) * 64;
    int hw0 = (rem & 63) * 64;
    int t = threadIdx.x;
    const float* zp = z + (size_t)b * DIM * HWSZ;
    {
        int hw4 = (t & 15) * 4, cl = t >> 4;
#pragma unroll
        for (int i = 0; i < 4; ++i) {
            int c = cl + i * 16;
            float4 v = *(const float4*)(zp + (size_t)(c0 + c) * HWSZ + hw0 + hw4);
            T[c][hw4 + 0] = v.x; T[c][hw4 + 1] = v.y;
            T[c][hw4 + 2] = v.z; T[c][hw4 + 3] = v.w;
        }
    }
    __syncthreads();
    // enc fp32 (output 0)
    {
        int c4 = (t & 15) * 4, hwl = t >> 4;
#pragma unroll
        for (int i = 0; i < 4; ++i) {
            int hw = hwl + i * 16;
            float4 v;
            v.x = T[c4 + 0][hw]; v.y = T[c4 + 1][hw];
            v.z = T[c4 + 2][hw]; v.w = T[c4 + 3][hw];
            *(float4*)(enc + (size_t)(b * HWSZ + hw0 + hw) * DIM + c0 + c4) = v;
        }
    }
    // fragment-layout fp16 hi/lo
    {
        int base_nb = b * 256 + (hw0 >> 4);
#pragma unroll
        for (int i = 0; i < 2; ++i) {
            int gidx = i * 256 + t;
            int nbi = gidx >> 7;
            int si = (gidx >> 6) & 1;
            int dq = (gidx >> 4) & 3;
            int r = gidx & 15;
            int hwl = nbi * 16 + r;
            int cl = si * 32 + dq * 8;
            h8 hi, lo;
#pragma unroll
            for (int j = 0; j < 8; ++j) {
                float x = T[cl + j][hwl];
                _Float16 h = (_Float16)x;
                hi[j] = h;
                lo[j] = (_Float16)(x - (float)h);
            }
            size_t G = (((size_t)(base_nb + nbi) * 8) + (c0 >> 5) + si) * 64 + dq * 16 + r;
            *(h8*)(AhF + G * 8) = hi;
            *(h8*)(AlF + G * 8) = lo;
        }
    }
}

// ---- K2: GEMM (fp16 split, 3 passes), 256x256 tile, rchunk-major grid -------
#define WAITV(n) asm volatile("s_waitcnt vmcnt(" #n ")" ::: "memory")
#define BARRIER __builtin_amdgcn_s_barrier()
#define PRIO1 __builtin_amdgcn_s_setprio(1)
#define PRIO0 __builtin_amdgcn_s_setprio(0)

extern __shared__ char SB[];   // 4 bufs x 32 KB = 128 KB; buf = [A 16KB][B 16KB]

__global__ __launch_bounds__(1024)
void k_gemm_argmin(const _Float16* __restrict__ AhF, const _Float16* __restrict__ AlF,
                   const _Float16* __restrict__ BhF, const _Float16* __restrict__ BlF,
                   const float* __restrict__ e_sq,
                   float* __restrict__ pV1, int* __restrict__ pI1) {
    int gid = blockIdx.x;
    // rchunk-major: 8-MB A chunks (32 rowTiles) reused across all 4 colTiles
    // before moving on -> A stays L3-hot (R6's proven ordering).
    int grp = gid >> 7;
    int colTile = (gid >> 5) & 3;
    int rowTile = grp * 32 + (gid & 31);
    int r0 = rowTile * 256, c0 = colTile * 256;
    int t = threadIdx.x;
    int w = t >> 6, l = t & 63;           // 16 waves
    int wm = w >> 2, wn = w & 3;          // wave tile 64x64
    int l16 = l & 15, lhi = l >> 4;

    // every wave stages 1 A-chunk + 1 B-chunk (1 KB each) per phase
    const char* gAh = (const char*)AhF + (((size_t)(rowTile * 16 + w)) << 13) + (l << 4);
    const char* gAl = (const char*)AlF + (((size_t)(rowTile * 16 + w)) << 13) + (l << 4);
    const char* gBh = (const char*)BhF + (((size_t)(colTile * 16 + w)) << 13) + (l << 4);
    const char* gBl = (const char*)BlF + (((size_t)(colTile * 16 + w)) << 13) + (l << 4);

#define ISSUE_P(p) do { \
    const int s_ = (p) >> 1; \
    char* bp_ = SB + ((p) & 3) * 32768; \
    const char* a_ = ((p) & 1) ? gAl : gAh; \
    const char* b_ = ((p) & 1) ? gBl : gBh; \
    gll16(a_ + (s_ << 10), bp_ + (w << 10)); \
    gll16(b_ + (s_ << 10), bp_ + 16384 + (w << 10)); \
} while (0)

#define MFMA16(A_, B_) { _Pragma("unroll") for (int mf = 0; mf < 4; ++mf) \
    _Pragma("unroll") for (int nf = 0; nf < 4; ++nf) \
        acc[mf][nf] = __builtin_amdgcn_mfma_f32_16x16x32_f16(A_[mf], B_[nf], acc[mf][nf], 0, 0, 0); }

// phase q: even = hh(step q/2); odd = hl + lh (step q/2)
#define PHASE(q, W, DO_ISSUE) { \
    WAITV(W); \
    BARRIER; \
    if (DO_ISSUE) ISSUE_P((q) + 3); \
    const char* bp_ = SB + ((q) & 3) * 32768; \
    if (((q) & 1) == 0) { \
        _Pragma("unroll") for (int mf = 0; mf < 4; ++mf) \
            ah[mf] = *(const h8*)(bp_ + ((wm * 4 + mf) << 10) + (l << 4)); \
        _Pragma("unroll") for (int nf = 0; nf < 4; ++nf) \
            bh[nf] = *(const h8*)(bp_ + 16384 + ((wn * 4 + nf) << 10) + (l << 4)); \
        PRIO1; MFMA16(ah, bh); PRIO0; \
    } else { \
        h8 xl[4]; \
        _Pragma("unroll") for (int nf = 0; nf < 4; ++nf) \
            xl[nf] = *(const h8*)(bp_ + 16384 + ((wn * 4 + nf) << 10) + (l << 4)); \
        PRIO1; MFMA16(ah, xl); PRIO0; \
        _Pragma("unroll") for (int mf = 0; mf < 4; ++mf) \
            xl[mf] = *(const h8*)(bp_ + ((wm * 4 + mf) << 10) + (l << 4)); \
        PRIO1; MFMA16(xl, bh); PRIO0; \
    } }

    f4 acc[4][4];
#pragma unroll
    for (int i = 0; i < 4; ++i)
#pragma unroll
        for (int j = 0; j < 4; ++j) acc[i][j] = (f4)0.0f;

    h8 ah[4], bh[4];

    // prologue: 3 phases in flight (6 loads per wave)
    ISSUE_P(0); ISSUE_P(1); ISSUE_P(2);

    PHASE(0, 4, 1)   PHASE(1, 4, 1)   PHASE(2, 4, 1)   PHASE(3, 4, 1)
    PHASE(4, 4, 1)   PHASE(5, 4, 1)   PHASE(6, 4, 1)   PHASE(7, 4, 1)
    PHASE(8, 4, 1)   PHASE(9, 4, 1)   PHASE(10, 4, 1)  PHASE(11, 4, 1)
    PHASE(12, 4, 1)  PHASE(13, 4, 0)  PHASE(14, 2, 0)  PHASE(15, 0, 0)

    // ---- scores + per-row argmin over this block's 256 codes ----
    // overlay buf0 region (phase 15 read buf3; all earlier bufs' readers done)
    float* smV = (float*)SB;          // [4][256]
    int* smI = (int*)(SB + 4096);     // [4][256]

    float esq[4];
#pragma unroll
    for (int nf = 0; nf < 4; ++nf) esq[nf] = e_sq[c0 + wn * 64 + nf * 16 + l16];

#pragma unroll
    for (int mf = 0; mf < 4; ++mf) {
#pragma unroll
        for (int rg = 0; rg < 4; ++rg) {
            float bestV = 3.4e38f;
            int bestI = 0;
#pragma unroll
            for (int nf = 0; nf < 4; ++nf) {
                float v = esq[nf] - 2.0f * acc[mf][nf][rg];
                int ci = c0 + wn * 64 + nf * 16 + l16;
                if (v < bestV || (v == bestV && ci < bestI)) { bestV = v; bestI = ci; }
            }
#pragma unroll
            for (int off = 1; off < 16; off <<= 1) {
                float vv = __shfl_xor(bestV, off);
                int ii = __shfl_xor(bestI, off);
                if (vv < bestV || (vv == bestV && ii < bestI)) { bestV = vv; bestI = ii; }
            }
            if (l16 == 0) {
                int rloc = wm * 64 + mf * 16 + lhi * 4 + rg;
                smV[wn * 256 + rloc] = bestV;
                smI[wn * 256 + rloc] = bestI;
            }
        }
    }
    __syncthreads();
    if (t < 256) {
        float bestV = smV[t];
        int bestI = smI[t];
#pragma unroll
        for (int wn2 = 1; wn2 < 4; ++wn2) {
            float v = smV[wn2 * 256 + t];
            int i2 = smI[wn2 * 256 + t];
            if (v < bestV || (v == bestV && i2 < bestI)) { bestV = v; bestI = i2; }
        }
        pV1[colTile * N_TOK + r0 + t] = bestV;
        pI1[colTile * N_TOK + r0 + t] = bestI;
    }
}

// ------ K3: combine partials -> final index, then gather quantized_flat ------
__global__ void k_final_out1(const float* __restrict__ pV1, const int* __restrict__ pI1,
                             const float* __restrict__ emb,
                             float* __restrict__ out2, int* __restrict__ idxI,
                             float* __restrict__ out1) {
    __shared__ int sidx[256];
    int t = threadIdx.x;
    int n0 = blockIdx.x * 256;
    int n = n0 + t;
    float v1 = pV1[n];
    int i1 = pI1[n];
#pragma unroll
    for (int ct = 1; ct < 4; ++ct) {
        float a1 = pV1[ct * N_TOK + n];
        int ai = pI1[ct * N_TOK + n];
        if (a1 < v1 || (a1 == v1 && ai < i1)) { v1 = a1; i1 = ai; }
    }
    out2[n] = (float)i1;
    idxI[n] = i1;
    sidx[t] = i1;
    __syncthreads();
    int rr = t >> 2, q = t & 3;
#pragma unroll
    for (int i = 0; i < 4; ++i) {
        int r = i * 64 + rr;
        int idx = sidx[r];
        const float* src = emb + (size_t)idx * DIM + q * 64;
        float* dst = out1 + (size_t)(n0 + r) * DIM + q * 64;
#pragma unroll
        for (int j = 0; j < 16; ++j)
            *(float4*)(dst + j * 4) = *(const float4*)(src + j * 4);
    }
}

// ---------------- K4: quantized[B,C,H,W] via LDS transpose -------------------
__global__ void k_out3(const float* __restrict__ emb, const int* __restrict__ idxI,
                       float* __restrict__ out3) {
    __shared__ float E[32][257];
    int blk = blockIdx.x;
    int b = blk >> 7, hwt = blk & 127;
    int hw0 = hwt * 32;
    int n0 = b * HWSZ + hw0;
    int t = threadIdx.x;
    {
        int r = t >> 3, oct = t & 7;
        int idx = idxI[n0 + r];
        const float* src = emb + (size_t)idx * DIM + oct * 32;
#pragma unroll
        for (int i = 0; i < 8; ++i) {
            float4 v = *(const float4*)(src + i * 4);
            E[r][oct * 32 + i * 4 + 0] = v.x;
            E[r][oct * 32 + i * 4 + 1] = v.y;
            E[r][oct * 32 + i * 4 + 2] = v.z;
            E[r][oct * 32 + i * 4 + 3] = v.w;
        }
    }
    __syncthreads();
    {
        int w = t >> 6, l = t & 63;
        int ch = l >> 5, hw = l & 31;
        float* dst = out3 + (size_t)b * DIM * HWSZ + hw0 + hw;
#pragma unroll
        for (int it = 0; it < 32; ++it) {
            int c = w * 64 + it * 2 + ch;
            dst[(size_t)c * HWSZ] = E[hw][c];
        }
    }
}

extern "C" void kernel_launch(void* const* d_in, const int* in_sizes, int n_in,
                              void* d_out, int out_size, void* d_ws, size_t ws_size,
                              hipStream_t stream) {
    const float* z = (const float*)d_in[0];
    const float* emb = (const float*)d_in[1];
    float* out = (float*)d_out;
    float* out0 = out;                    // encoded_flat  [65536,256]
    float* out1 = out + 16777216;         // quantized_flat[65536,256]
    float* out2 = out + 33554432;         // indices       [65536] (as float)
    float* out3 = out + 33619968;         // quantized     [16,256,64,64]

    // A-operand fp16 hi/lo scratch fills the out1 region (64 MB); out1 is
    // written afterwards by k_final_out1.
    _Float16* AhF = (_Float16*)out1;
    _Float16* AlF = (_Float16*)(out1 + 8388608);

    char* ws = (char*)d_ws;
    _Float16* BhF = (_Float16*)(ws);                 // 512 KB
    _Float16* BlF = (_Float16*)(ws + 524288);        // 512 KB
    float* e_sq = (float*)(ws + 1048576);            // 4 KB
    float* pV1 = (float*)(ws + 1052672);             // 1 MB
    int* pI1 = (int*)(ws + 2101248);                 // 1 MB
    int* idxI = (int*)(ws + 3149824);                // 256 KB

    hipFuncSetAttribute((const void*)k_gemm_argmin,
                        hipFuncAttributeMaxDynamicSharedMemorySize, 131072);

    k_prep_frag<<<128, 256, 0, stream>>>(emb, BhF, BlF);
    k_esq<<<256, 256, 0, stream>>>(emb, e_sq);
    k_transpose<<<4096, 256, 0, stream>>>(z, out0, AhF, AlF);
    k_gemm_argmin<<<1024, 1024, 131072, stream>>>(AhF, AlF, BhF, BlF, e_sq, pV1, pI1);
    k_final_out1<<<256, 256, 0, stream>>>(pV1, pI1, emb, out2, idxI, out1);
    k_out3<<<2048, 256, 0, stream>>>(emb, idxI, out3);
}